// Round 3
// baseline (1242.757 us; speedup 1.0000x reference)
//
#include <hip/hip_runtime.h>
#include <hip/hip_bf16.h>

// Problem dims (fixed by reference): x[B*S=8192, E=2048], w1/w2[H=8192, E], w3[E, H]
#define M_ROWS 8192
#define E_DIM  2048
#define H_DIM  8192

typedef __attribute__((ext_vector_type(8))) short bf16x8;
typedef __attribute__((ext_vector_type(4))) float f32x4;
typedef __attribute__((ext_vector_type(4))) unsigned int uint4v;

__device__ __forceinline__ unsigned short f2bf_rne(float x) {
  unsigned u = __builtin_bit_cast(unsigned, x);
  u += 0x7FFFu + ((u >> 16) & 1u);
  return (unsigned short)(u >> 16);
}

__device__ __forceinline__ float bf2f(unsigned short b) {
  unsigned u = ((unsigned)b) << 16;
  return __builtin_bit_cast(float, u);
}

// ---------------- fp32 -> bf16 conversion (memory-bound, vectorized) ----------------
__global__ __launch_bounds__(256) void cvt_f32_bf16(const float* __restrict__ in,
                                                    unsigned short* __restrict__ out,
                                                    int n8) {
  int i = blockIdx.x * blockDim.x + threadIdx.x;
  if (i >= n8) return;
  const float4* p = (const float4*)(in + (size_t)i * 8);
  float4 a = p[0];
  float4 b = p[1];
  union { unsigned short us[8]; uint4v v; } r;
  r.us[0] = f2bf_rne(a.x); r.us[1] = f2bf_rne(a.y);
  r.us[2] = f2bf_rne(a.z); r.us[3] = f2bf_rne(a.w);
  r.us[4] = f2bf_rne(b.x); r.us[5] = f2bf_rne(b.y);
  r.us[6] = f2bf_rne(b.z); r.us[7] = f2bf_rne(b.w);
  *(uint4v*)(out + (size_t)i * 8) = r.v;
}

// ---------------- async global -> LDS, 16B per lane ----------------
__device__ __forceinline__ void gld_lds16(const unsigned short* g, unsigned short* l) {
  __builtin_amdgcn_global_load_lds(
      (const __attribute__((address_space(1))) unsigned int*)g,
      (__attribute__((address_space(3))) unsigned int*)l, 16, 0, 0);
}

#define VMCNT(n) asm volatile("s_waitcnt vmcnt(" #n ")" ::: "memory")

// =============== 256x256 8-phase GEMM: C[M,N] = A[M,K] * B[N,K]^T ===============
// 512 threads (8 waves, 2Mx4N), BK=64, double-buffered 128KiB LDS, counted vmcnt(4),
// XOR-swizzled LDS (elem ^= (row&7)<<3) via pre-swizzled global source (linear LDS dest),
// setprio around MFMA clusters, bijective XCD swizzle on block id.
// Safety invariants:
//  - all ds_reads of buf[t] are issued in phases 1-2 and consumed (lgkm) before ph2's
//    trailing barrier; phases 3-4 only overwrite buf[t]'s A halves (read-complete).
//  - tile t+1's B halves are staged (ph1,ph2) into buf[t^1], last read at tile t-1.
//  - vmcnt(4) at ph4 (before trailing barrier) => tile t+1 fully landed; leaves
//    t+2's A halves (4 loads) in flight. Tail tiles drop to vmcnt(0).
// EPI=0: fp32 store; EPI=1: bf16 store; EPI=2: bf16 silu(Gate[idx]) * acc store.
template <int EPI>
__global__ __launch_bounds__(512, 2)
void gemm256(const unsigned short* __restrict__ A,
             const unsigned short* __restrict__ B,
             const unsigned short* __restrict__ Gate,
             void* __restrict__ Cout,
             int M, int N, int K) {
  __shared__ unsigned short lA[2][16384];  // 2 x 256x64 bf16 (2 halves of 128x64)
  __shared__ unsigned short lB[2][16384];

  const int tid = threadIdx.x;
  const int lane = tid & 63;
  const int wave = tid >> 6;
  const int wr = wave >> 2;   // 0..1  (128 output rows each)
  const int wc = wave & 3;    // 0..3  (64 output cols each)
  const int lr = lane & 15, lk = lane >> 4;

  // bijective XCD swizzle (nwg % 8 == 0 for all launches here)
  const int gx = gridDim.x;
  const int nwg = gx * gridDim.y;
  const int wg = blockIdx.y * gx + blockIdx.x;
  const int swz = (wg & 7) * (nwg >> 3) + (wg >> 3);
  const int bcol = swz % gx, brow = swz / gx;

  const unsigned short* Ag = A + (size_t)brow * 256 * K;
  const unsigned short* Bg = B + (size_t)bcol * 256 * K;

  f32x4 acc[8][4] = {};
  const int NT = K >> 6;

  // stage one 128x64 half-tile: linear LDS dest (lane*16B), inverse-swizzled global src
  auto stage = [&](const unsigned short* gbase, unsigned short* ldsh) {
#pragma unroll
    for (int i = 0; i < 2; ++i) {
      int p = i * 4096 + tid * 8;               // physical element offset in half
      int row = p >> 6;                          // 0..127
      int lslot = ((p >> 3) & 7) ^ (row & 7);    // logical 8-elem slot
      gld_lds16(gbase + (size_t)row * K + lslot * 8, ldsh + p);
    }
  };

  // ---------------- prologue: tile0 (A0,A1,B0,B1) + tile1 (A0,A1) ----------------
  stage(Ag, &lA[0][0]);
  stage(Ag + (size_t)128 * K, &lA[0][8192]);
  stage(Bg, &lB[0][0]);
  stage(Bg + (size_t)128 * K, &lB[0][8192]);
  if (NT > 1) {
    stage(Ag + 64, &lA[1][0]);
    stage(Ag + (size_t)128 * K + 64, &lA[1][8192]);
    VMCNT(4);
  } else {
    VMCNT(0);
  }
  __builtin_amdgcn_s_barrier();

  const int xsw = (lr & 7) << 3;  // read-side swizzle XOR (element units)

  for (int t = 0; t < NT; ++t) {
    const int cur = t & 1;
    const unsigned short* lAc = &lA[cur][0];
    const unsigned short* lBc = &lB[cur][0];
    unsigned short* lAn = &lA[cur][0];        // t+2 has same parity as t
    unsigned short* lBn = &lB[cur ^ 1][0];    // t+1 parity
    const size_t kn1 = (size_t)(t + 1) * 64;
    const size_t kn2 = (size_t)(t + 2) * 64;

    bf16x8 af[8][2], bf[4][2];

    // ---- phase 1: read A m0-3 (8) + B n0-1 (4); stage (t+1).B0; MFMA Q0 m0-3 x n0-1
#pragma unroll
    for (int m = 0; m < 4; ++m)
#pragma unroll
      for (int ks = 0; ks < 2; ++ks) {
        int r = wr * 128 + m * 16 + lr;
        af[m][ks] = *(const bf16x8*)&lAc[(r * 64 + ks * 32 + lk * 8) ^ xsw];
      }
#pragma unroll
    for (int n = 0; n < 2; ++n)
#pragma unroll
      for (int ks = 0; ks < 2; ++ks) {
        int r = wc * 64 + n * 16 + lr;
        bf[n][ks] = *(const bf16x8*)&lBc[(r * 64 + ks * 32 + lk * 8) ^ xsw];
      }
    if (t + 1 < NT) stage(Bg + kn1, lBn);
    __builtin_amdgcn_s_barrier();
    __builtin_amdgcn_s_setprio(1);
#pragma unroll
    for (int m = 0; m < 4; ++m)
#pragma unroll
      for (int n = 0; n < 2; ++n)
#pragma unroll
        for (int ks = 0; ks < 2; ++ks)
          acc[m][n] = __builtin_amdgcn_mfma_f32_16x16x32_bf16(af[m][ks], bf[n][ks], acc[m][n], 0, 0, 0);
    __builtin_amdgcn_s_setprio(0);
    __builtin_amdgcn_s_barrier();

    // ---- phase 2: read A m4-7 (8) + B n2-3 (4); stage (t+1).B1; MFMA Q1 m4-7 x n0-1
#pragma unroll
    for (int m = 4; m < 8; ++m)
#pragma unroll
      for (int ks = 0; ks < 2; ++ks) {
        int r = wr * 128 + m * 16 + lr;
        af[m][ks] = *(const bf16x8*)&lAc[(r * 64 + ks * 32 + lk * 8) ^ xsw];
      }
#pragma unroll
    for (int n = 2; n < 4; ++n)
#pragma unroll
      for (int ks = 0; ks < 2; ++ks) {
        int r = wc * 64 + n * 16 + lr;
        bf[n][ks] = *(const bf16x8*)&lBc[(r * 64 + ks * 32 + lk * 8) ^ xsw];
      }
    if (t + 1 < NT) stage(Bg + (size_t)128 * K + kn1, lBn + 8192);
    __builtin_amdgcn_s_barrier();
    __builtin_amdgcn_s_setprio(1);
#pragma unroll
    for (int m = 4; m < 8; ++m)
#pragma unroll
      for (int n = 0; n < 2; ++n)
#pragma unroll
        for (int ks = 0; ks < 2; ++ks)
          acc[m][n] = __builtin_amdgcn_mfma_f32_16x16x32_bf16(af[m][ks], bf[n][ks], acc[m][n], 0, 0, 0);
    __builtin_amdgcn_s_setprio(0);
    __builtin_amdgcn_s_barrier();

    // ---- phase 3: stage (t+2).A0 (into buf[t], A reads complete); MFMA Q2 m0-3 x n2-3
    if (t + 2 < NT) stage(Ag + kn2, lAn);
    __builtin_amdgcn_s_barrier();
    __builtin_amdgcn_s_setprio(1);
#pragma unroll
    for (int m = 0; m < 4; ++m)
#pragma unroll
      for (int n = 2; n < 4; ++n)
#pragma unroll
        for (int ks = 0; ks < 2; ++ks)
          acc[m][n] = __builtin_amdgcn_mfma_f32_16x16x32_bf16(af[m][ks], bf[n][ks], acc[m][n], 0, 0, 0);
    __builtin_amdgcn_s_setprio(0);
    __builtin_amdgcn_s_barrier();

    // ---- phase 4: stage (t+2).A1; MFMA Q3 m4-7 x n2-3; counted vmcnt; barrier
    if (t + 2 < NT) stage(Ag + (size_t)128 * K + kn2, lAn + 8192);
    __builtin_amdgcn_s_barrier();
    __builtin_amdgcn_s_setprio(1);
#pragma unroll
    for (int m = 4; m < 8; ++m)
#pragma unroll
      for (int n = 2; n < 4; ++n)
#pragma unroll
        for (int ks = 0; ks < 2; ++ks)
          acc[m][n] = __builtin_amdgcn_mfma_f32_16x16x32_bf16(af[m][ks], bf[n][ks], acc[m][n], 0, 0, 0);
    __builtin_amdgcn_s_setprio(0);
    if (t + 2 < NT) { VMCNT(4); } else { VMCNT(0); }
    __builtin_amdgcn_s_barrier();
  }

  // Epilogue. C/D frag layout (measured, m89/m91): col = lane&15, row = (lane>>4)*4 + j
  const int row0 = brow * 256 + wr * 128 + lk * 4;
  const int col0 = bcol * 256 + wc * 64 + lr;
#pragma unroll
  for (int m = 0; m < 8; ++m) {
#pragma unroll
    for (int n = 0; n < 4; ++n) {
#pragma unroll
      for (int j = 0; j < 4; ++j) {
        size_t idx = (size_t)(row0 + m * 16 + j) * N + (col0 + n * 16);
        float v = acc[m][n][j];
        if constexpr (EPI == 0) {
          ((float*)Cout)[idx] = v;
        } else if constexpr (EPI == 1) {
          ((unsigned short*)Cout)[idx] = f2bf_rne(v);
        } else {
          float g = bf2f(Gate[idx]);
          float s = g / (1.0f + __expf(-g));  // silu
          ((unsigned short*)Cout)[idx] = f2bf_rne(s * v);
        }
      }
    }
  }
}

extern "C" void kernel_launch(void* const* d_in, const int* in_sizes, int n_in,
                              void* d_out, int out_size, void* d_ws, size_t ws_size,
                              hipStream_t stream) {
  const float* x  = (const float*)d_in[0];
  const float* w1 = (const float*)d_in[1];
  const float* w2 = (const float*)d_in[2];
  const float* w3 = (const float*)d_in[3];
  float* out = (float*)d_out;

  const int M = M_ROWS, E = E_DIM, H = H_DIM;

  // ws layout (bf16 elements):
  //   [0, 32MB)   xb   (reused for w3b after up-GEMM)
  //   [32, 64MB)  w1b  (reused for w2b after gate-GEMM)
  //   [64, 192MB) gate -> h (silu-mul written in-place)
  unsigned short* xb  = (unsigned short*)d_ws;
  unsigned short* w1b = xb + (size_t)M * E;
  unsigned short* gb  = w1b + (size_t)H * E;
  unsigned short* w2b = w1b;  // safe: cvt(w2) is stream-ordered after gate-GEMM reads w1b
  unsigned short* w3b = xb;   // safe: cvt(w3) is stream-ordered after up-GEMM reads xb

  const int n8 = (M * E) / 8;  // == (H*E)/8 == (E*H)/8 == 2097152
  cvt_f32_bf16<<<dim3(n8 / 256), 256, 0, stream>>>(x, xb, n8);
  cvt_f32_bf16<<<dim3(n8 / 256), 256, 0, stream>>>(w1, w1b, n8);

  // gate = x w1^T  -> bf16 [M, H]
  gemm256<1><<<dim3(H / 256, M / 256), 512, 0, stream>>>(xb, w1b, nullptr, gb, M, H, E);

  cvt_f32_bf16<<<dim3(n8 / 256), 256, 0, stream>>>(w2, w2b, n8);

  // h = silu(gate) * (x w2^T) -> bf16 [M, H], in-place over gate
  gemm256<2><<<dim3(H / 256, M / 256), 512, 0, stream>>>(xb, w2b, gb, gb, M, H, E);

  cvt_f32_bf16<<<dim3(n8 / 256), 256, 0, stream>>>(w3, w3b, n8);

  // out = h w3^T -> fp32 [M, E]
  gemm256<0><<<dim3(E / 256, M / 256), 512, 0, stream>>>(gb, w3b, nullptr, out, M, E, H);
}